// Round 5
// baseline (221.792 us; speedup 1.0000x reference)
//
#include <hip/hip_runtime.h>

// Problem: B=4, T=2048, C=1024, H=16, D=64.  x:[B,T,C] f32, w:[C,3C] f32.
// Plan: x -> bf16 (scratch in d_out) ; w -> w^T bf16 ; m97-style MFMA GEMM
//       (global_load_lds, swizzled LDS) -> q,k,v [B,H,T,D] bf16 ;
//       flash attention (causal, fixed-max softmax) -> out f32 [B,T,C].
// R3: swapped QK^T (mfma(K,Q) -> S^T), 32x32x16 MFMA, in-register softmax
//     (cvt_pk_bf16 pack + shfl_xor(32) half-exchange). Verified correct.
// R4: one 64-row q-tile per 128-thread block (2 waves, equal extent);
//     2048 blocks = 8/CU; per-CU complementary-extent qt map.
// R5: fix R4's bug — attn was still launched with 256 threads/block while the
//     kernel's staging geometry assumes 128 (Kl writes ran to row 79 -> V
//     corruption). Launch now <<< (32,64), 128 >>>.

#define B_ 4
#define T_ 2048
#define C_ 1024
#define H_ 16
#define D_ 64
#define QKV1 (B_*H_*T_*D_)   // 8,388,608 elements per q/k/v

typedef __attribute__((ext_vector_type(4)))  float  f32x4;
typedef __attribute__((ext_vector_type(16))) float  f32x16;
typedef __attribute__((ext_vector_type(8)))  short  bf16x8;
typedef __attribute__((ext_vector_type(4)))  unsigned int u32x4;

__device__ inline unsigned short f2bf(float f) {
  unsigned int u = __builtin_bit_cast(unsigned int, f);
  u += 0x7FFFu + ((u >> 16) & 1u);          // RNE
  return (unsigned short)(u >> 16);
}

__device__ inline void gload16(const unsigned short* g, unsigned short* l) {
  __builtin_amdgcn_global_load_lds(
      (const __attribute__((address_space(1))) void*)g,
      (__attribute__((address_space(3))) void*)l, 16, 0, 0);
}

// ---------------- x [8192][1024] f32 -> xb bf16 ----------------
__global__ __launch_bounds__(256) void convert_x(const float* __restrict__ x,
                                                 unsigned short* __restrict__ xb) {
  size_t i = ((size_t)blockIdx.x * 256 + threadIdx.x) * 16;
  f32x4 a = *(const f32x4*)(x + i);
  f32x4 b = *(const f32x4*)(x + i + 4);
  f32x4 c = *(const f32x4*)(x + i + 8);
  f32x4 d = *(const f32x4*)(x + i + 12);
  bf16x8 o0, o1;
#pragma unroll
  for (int j = 0; j < 4; j++) {
    o0[j]     = (short)f2bf(a[j]);
    o0[j + 4] = (short)f2bf(b[j]);
    o1[j]     = (short)f2bf(c[j]);
    o1[j + 4] = (short)f2bf(d[j]);
  }
  *(bf16x8*)(xb + i) = o0;
  *(bf16x8*)(xb + i + 8) = o1;
}

// ---------------- w [1024][3072] f32 -> wt [3072][1024] bf16 ----------------
__global__ __launch_bounds__(256) void transpose_w(const float* __restrict__ w,
                                                   unsigned short* __restrict__ wt) {
  __shared__ float tile[32][33];
  const int tx = threadIdx.x & 31, ty = threadIdx.x >> 5;   // 32 x 8
  const int n0 = blockIdx.x * 32, k0 = blockIdx.y * 32;
#pragma unroll
  for (int j = 0; j < 4; j++) {
    int k = ty + j * 8;
    tile[k][tx] = w[(size_t)(k0 + k) * 3072 + n0 + tx];
  }
  __syncthreads();
#pragma unroll
  for (int j = 0; j < 4; j++) {
    int n = ty + j * 8;
    wt[(size_t)(n0 + n) * 1024 + k0 + tx] = f2bf(tile[tx][n]);
  }
}

// ---------------- QKV GEMM: [8192,1024]bf16 x [1024,3072]bf16 -> bf16 qkv ----------------
// BM=BN=128, BK=64, 256 threads (4 waves 2x2, wave tile 64x64), 16x16x32 MFMA.
__global__ __launch_bounds__(256) void qkv_gemm(const unsigned short* __restrict__ xb,
                                                const unsigned short* __restrict__ wt,
                                                unsigned short* __restrict__ qkv) {
  __shared__ unsigned short Al[128 * 64];   // 16 KB
  __shared__ unsigned short Bl[128 * 64];   // 16 KB
  const int tid = threadIdx.x;
  const int lane = tid & 63, wid = tid >> 6;
  const int l15 = lane & 15, g = lane >> 4;
  const int m0 = blockIdx.y * 128, n0 = blockIdx.x * 128;
  const int wm = (wid >> 1) * 64, wn = (wid & 1) * 64;

  f32x4 acc[4][4] = {};

  const int srow[4] = { (0 * 256 + tid) >> 3, (1 * 256 + tid) >> 3,
                        (2 * 256 + tid) >> 3, (3 * 256 + tid) >> 3 };
  int scol[4];
#pragma unroll
  for (int sw = 0; sw < 4; sw++) {
    int s = sw * 256 + tid;
    scol[sw] = (s & 7) ^ (srow[sw] & 7);
  }

  for (int k0 = 0; k0 < 1024; k0 += 64) {
    __syncthreads();
#pragma unroll
    for (int sw = 0; sw < 4; sw++) {
      unsigned short* ldsA = &Al[(sw * 256 + wid * 64) * 8];  // wave-uniform base
      unsigned short* ldsB = &Bl[(sw * 256 + wid * 64) * 8];
      gload16(xb + (size_t)(m0 + srow[sw]) * 1024 + k0 + scol[sw] * 8, ldsA);
      gload16(wt + (size_t)(n0 + srow[sw]) * 1024 + k0 + scol[sw] * 8, ldsB);
    }
    __syncthreads();

#pragma unroll
    for (int ks = 0; ks < 2; ks++) {
      bf16x8 af[4], bfr[4];
#pragma unroll
      for (int mt = 0; mt < 4; mt++) {
        int row = wm + mt * 16 + l15;
        int c = (ks * 4 + g) ^ (row & 7);
        af[mt] = *(const bf16x8*)&Al[(row * 8 + c) * 8];
      }
#pragma unroll
      for (int nt = 0; nt < 4; nt++) {
        int row = wn + nt * 16 + l15;
        int c = (ks * 4 + g) ^ (row & 7);
        bfr[nt] = *(const bf16x8*)&Bl[(row * 8 + c) * 8];
      }
#pragma unroll
      for (int mt = 0; mt < 4; mt++)
#pragma unroll
        for (int nt = 0; nt < 4; nt++)
          acc[mt][nt] = __builtin_amdgcn_mfma_f32_16x16x32_bf16(af[mt], bfr[nt], acc[mt][nt], 0, 0, 0);
    }
  }

  const int r0 = g * 4, cc = l15;
#pragma unroll
  for (int mt = 0; mt < 4; mt++)
#pragma unroll
    for (int nt = 0; nt < 4; nt++)
#pragma unroll
      for (int r = 0; r < 4; r++) {
        int m = m0 + wm + mt * 16 + r0 + r;
        int n = n0 + wn + nt * 16 + cc;
        int b = m >> 11, t = m & 2047;
        int which = n >> 10, c = n & 1023;
        int h = c >> 6, d = c & 63;
        qkv[(size_t)which * QKV1 + ((size_t)((b * H_ + h) * T_ + t)) * D_ + d] =
            f2bf(acc[mt][nt][r]);
      }
}

// ---------------- causal flash attention, swapped 32x32 MFMA, in-reg softmax ----------
// grid (32, B*H), 128 threads. Wave wq handles rows q0 = qt*64 + wq*32.
// S^T = mfma(K, Q): lane (q=lane&31, hi=lane>>5) holds S[k][q] for
// k = (r&3)+8*(r>>2)+4*hi per 32-k tile. P packed to bf16 pairs in-register;
// halves exchange 8 u32 via shfl_xor(32).
// qt map: per-CU complementary extents AND bijective in blockIdx.x per bh:
// j=bh>>3, g=(x + (j>>1)*8)&31, qt = (j&1)? 31-g : g.
__global__ __launch_bounds__(128, 4) void attn(const unsigned short* __restrict__ qkv,
                                               float* __restrict__ out) {
  __shared__ unsigned short Kl[64][72];     // [k][d]
  __shared__ unsigned short Vl[64][72];     // transposed [d][k], k XOR-swizzled
  __shared__ float RSl[2][32];
  const int tid = threadIdx.x, lane = tid & 63, wq = tid >> 6;  // wq 0..1
  const int l31 = lane & 31, hi = lane >> 5;
  const int bh = blockIdx.y;
  const int jj = bh >> 3;
  const int gg = (blockIdx.x + (jj >> 1) * 8) & 31;
  const int qt = (jj & 1) ? (31 - gg) : gg;
  const int ntiles = qt + 1;
  const int q0 = qt * 64 + wq * 32;
  const size_t base = (size_t)bh * (T_ * D_);
  const unsigned short* qp = qkv + base;
  const unsigned short* kp = qkv + (size_t)QKV1 + base;
  const unsigned short* vp = qkv + 2 * (size_t)QKV1 + base;

  // Q fragments (B-operand of mfma(K,Q)): lane holds Q[q0+l31][c*16+hi*8+j],
  // scaled by 1/sqrt(D) = 0.125.
  bf16x8 qf[4];
#pragma unroll
  for (int c = 0; c < 4; c++) {
    bf16x8 v = *(const bf16x8*)(qp + (size_t)(q0 + l31) * 64 + c * 16 + hi * 8);
#pragma unroll
    for (int j = 0; j < 8; j++) {
      unsigned int u = (unsigned int)(unsigned short)v[j] << 16;
      float f = __builtin_bit_cast(float, u) * 0.125f;
      v[j] = (short)f2bf(f);
    }
    qf[c] = v;
  }

  f32x16 o0 = {}, o1 = {};
  float rs = 0.f;

  bf16x8 kreg0, kreg1, kreg2, kreg3, vr00, vr01, vr10, vr11;
  const int krow = tid >> 3, kch = tid & 7;   // krow 0..15, kch 0..7
#define LOADKV(IT)                                                             \
  do {                                                                         \
    size_t k0_ = (size_t)(IT) * 64;                                            \
    kreg0 = *(const bf16x8*)(kp + (k0_ + krow)      * 64 + kch * 8);           \
    kreg1 = *(const bf16x8*)(kp + (k0_ + krow + 16) * 64 + kch * 8);           \
    kreg2 = *(const bf16x8*)(kp + (k0_ + krow + 32) * 64 + kch * 8);           \
    kreg3 = *(const bf16x8*)(kp + (k0_ + krow + 48) * 64 + kch * 8);           \
    vr00  = *(const bf16x8*)(vp + (k0_ + 2 * krow)          * 64 + kch * 8);   \
    vr01  = *(const bf16x8*)(vp + (k0_ + 2 * krow + 1)      * 64 + kch * 8);   \
    vr10  = *(const bf16x8*)(vp + (k0_ + 2 * (krow + 16))     * 64 + kch * 8); \
    vr11  = *(const bf16x8*)(vp + (k0_ + 2 * (krow + 16) + 1) * 64 + kch * 8); \
  } while (0)

  LOADKV(0);
  for (int it = 0; it < ntiles; ++it) {
    __syncthreads();
    *(bf16x8*)&Kl[krow][kch * 8]      = kreg0;
    *(bf16x8*)&Kl[krow + 16][kch * 8] = kreg1;
    *(bf16x8*)&Kl[krow + 32][kch * 8] = kreg2;
    *(bf16x8*)&Kl[krow + 48][kch * 8] = kreg3;
#pragma unroll
    for (int j = 0; j < 8; j++) {
      int d = kch * 8 + j;
      int sw = (d >> 3) << 3;
      unsigned int pk0 = ((unsigned int)(unsigned short)vr01[j] << 16) |
                         (unsigned int)(unsigned short)vr00[j];
      unsigned int pk1 = ((unsigned int)(unsigned short)vr11[j] << 16) |
                         (unsigned int)(unsigned short)vr10[j];
      *(unsigned int*)&Vl[d][(2 * krow) ^ sw]        = pk0;
      *(unsigned int*)&Vl[d][(2 * (krow + 16)) ^ sw] = pk1;
    }
    if (it + 1 < ntiles) LOADKV(it + 1);
    __syncthreads();

    // ---- QK^T (S^T) + in-register softmax + pack ----
    unsigned int pk_[16];   // 8 runs of 4 k-values, 2 u32 each; run t base k=8t+4*hi
#pragma unroll
    for (int kt = 0; kt < 2; kt++) {
      f32x16 s = {};
      __builtin_amdgcn_s_setprio(1);
#pragma unroll
      for (int c = 0; c < 4; c++) {
        bf16x8 kf = *(const bf16x8*)&Kl[kt * 32 + l31][c * 16 + hi * 8];
        s = __builtin_amdgcn_mfma_f32_32x32x16_bf16(kf, qf[c], s, 0, 0, 0);
      }
      __builtin_amdgcn_s_setprio(0);
      if (it == qt) {
#pragma unroll
        for (int r = 0; r < 16; r++) {
          int kg = it * 64 + kt * 32 + (r & 3) + 8 * (r >> 2) + 4 * hi;
          if (kg > q0 + l31) s[r] = -1e30f;
        }
      }
      float p[16];
#pragma unroll
      for (int r = 0; r < 16; r++) { p[r] = __expf(s[r]); rs += p[r]; }
#pragma unroll
      for (int t = 0; t < 4; t++) {
        unsigned int plo, phi;
        asm("v_cvt_pk_bf16_f32 %0, %1, %2" : "=v"(plo) : "v"(p[4*t]), "v"(p[4*t+1]));
        asm("v_cvt_pk_bf16_f32 %0, %1, %2" : "=v"(phi) : "v"(p[4*t+2]), "v"(p[4*t+3]));
        pk_[(kt * 4 + t) * 2]     = plo;
        pk_[(kt * 4 + t) * 2 + 1] = phi;
      }
    }

    // ---- half-exchange: hi=0 sends odd runs, hi=1 sends even runs ----
    unsigned int rcv0[4], rcv1[4];
#pragma unroll
    for (int j = 0; j < 4; j++) {
      unsigned int s0 = hi ? pk_[(2 * j) * 2]     : pk_[(2 * j + 1) * 2];
      unsigned int s1 = hi ? pk_[(2 * j) * 2 + 1] : pk_[(2 * j + 1) * 2 + 1];
      rcv0[j] = (unsigned int)__shfl_xor((int)s0, 32);
      rcv1[j] = (unsigned int)__shfl_xor((int)s1, 32);
    }

    // ---- PV: A = P (rows q=l31), B = V^T from LDS ----
    __builtin_amdgcn_s_setprio(1);
#pragma unroll
    for (int st = 0; st < 4; st++) {
      unsigned int u0 = hi ? rcv0[st]        : pk_[4 * st];
      unsigned int u1 = hi ? rcv1[st]        : pk_[4 * st + 1];
      unsigned int u2 = hi ? pk_[4 * st + 2] : rcv0[st];
      unsigned int u3 = hi ? pk_[4 * st + 3] : rcv1[st];
      u32x4 pu = {u0, u1, u2, u3};
      bf16x8 paf = __builtin_bit_cast(bf16x8, pu);
      int koff = st * 16 + hi * 8;
      bf16x8 vf0 = *(const bf16x8*)&Vl[l31][koff ^ ((l31 >> 3) << 3)];
      bf16x8 vf1 = *(const bf16x8*)&Vl[32 + l31][koff ^ (((32 + l31) >> 3) << 3)];
      o0 = __builtin_amdgcn_mfma_f32_32x32x16_bf16(paf, vf0, o0, 0, 0, 0);
      o1 = __builtin_amdgcn_mfma_f32_32x32x16_bf16(paf, vf1, o1, 0, 0, 0);
    }
    __builtin_amdgcn_s_setprio(0);
  }

  // ---- epilogue: rowsum across halves, redistribute via tiny LDS, store ----
  float rsf = rs + __shfl_xor(rs, 32);
  float inv = 1.0f / rsf;
  if (hi == 0) RSl[wq][l31] = inv;
  asm volatile("s_waitcnt lgkmcnt(0)" ::: "memory");
  const int b = bh >> 4, h = bh & 15;
#pragma unroll
  for (int r = 0; r < 16; r++) {
    int ql = (r & 3) + 8 * (r >> 2) + 4 * hi;
    float iv = RSl[wq][ql];
    int qg = q0 + ql;
    size_t o = ((size_t)(b * T_ + qg)) * C_ + h * 64;
    out[o + l31]      = o0[r] * iv;
    out[o + 32 + l31] = o1[r] * iv;
  }
}

extern "C" void kernel_launch(void* const* d_in, const int* in_sizes, int n_in,
                              void* d_out, int out_size, void* d_ws, size_t ws_size,
                              hipStream_t stream) {
  const float* x = (const float*)d_in[0];
  const float* w = (const float*)d_in[1];
  float* out = (float*)d_out;
  unsigned short* wt  = (unsigned short*)d_ws;            // 3072*1024 bf16 = 6 MB
  unsigned short* qkv = wt + (size_t)3072 * 1024;         // 3 * 8.4M bf16 = 48 MB
  // xb scratch lives in d_out (32 MB f32); attn fully overwrites it afterwards.
  unsigned short* xb  = (unsigned short*)d_out;           // 8192*1024 bf16 = 16 MB

  convert_x  <<<2048, 256, 0, stream>>>(x, xb);
  transpose_w<<<dim3(96, 32), 256, 0, stream>>>(w, wt);
  qkv_gemm   <<<dim3(24, 64), 256, 0, stream>>>(xb, wt, qkv);
  attn       <<<dim3(32, 64), 128, 0, stream>>>(qkv, out);
}

// Round 6
// 151.701 us; speedup vs baseline: 1.4620x; 1.4620x over previous
//
#include <hip/hip_runtime.h>

// Problem: B=4, T=2048, C=1024, H=16, D=64.  x:[B,T,C] f32, w:[C,3C] f32.
// Plan: x -> bf16 (scratch in d_out) ; w -> w^T bf16 ; m97-style MFMA GEMM
//       (global_load_lds, swizzled LDS) -> q,k,v [B,H,T,D] bf16 ;
//       flash attention (causal, fixed-max softmax) -> out f32 [B,T,C].
// R1: merged pair-processing in attn (shared K/V fragments between the two
//     q-tiles of a pair), double P buffer (one lgkm wait/iter), setprio(T5).
// R6: __launch_bounds__(256, 2) on attn. Empirical cap law: arg 4 -> 64 VGPR
//     (R0/R2/R5 spilled), arg 3 -> 84 (R1, squeezed), arg 2 -> ~128. Body
//     needs ~100: spill-free AND 4 blocks/CU (LDS 36.9KB*4=144KB, VGPR<=128).

#define B_ 4
#define T_ 2048
#define C_ 1024
#define H_ 16
#define D_ 64
#define QKV1 (B_*H_*T_*D_)   // 8,388,608 elements per q/k/v

typedef __attribute__((ext_vector_type(4))) float  f32x4;
typedef __attribute__((ext_vector_type(8))) short  bf16x8;
typedef __attribute__((ext_vector_type(4))) short  bf16x4;

__device__ inline unsigned short f2bf(float f) {
  unsigned int u = __builtin_bit_cast(unsigned int, f);
  u += 0x7FFFu + ((u >> 16) & 1u);          // RNE
  return (unsigned short)(u >> 16);
}

__device__ inline void gload16(const unsigned short* g, unsigned short* l) {
  __builtin_amdgcn_global_load_lds(
      (const __attribute__((address_space(1))) void*)g,
      (__attribute__((address_space(3))) void*)l, 16, 0, 0);
}

// ---------------- x [8192][1024] f32 -> xb bf16 ----------------
__global__ __launch_bounds__(256) void convert_x(const float* __restrict__ x,
                                                 unsigned short* __restrict__ xb) {
  size_t i = ((size_t)blockIdx.x * 256 + threadIdx.x) * 16;
  f32x4 a = *(const f32x4*)(x + i);
  f32x4 b = *(const f32x4*)(x + i + 4);
  f32x4 c = *(const f32x4*)(x + i + 8);
  f32x4 d = *(const f32x4*)(x + i + 12);
  bf16x8 o0, o1;
#pragma unroll
  for (int j = 0; j < 4; j++) {
    o0[j]     = (short)f2bf(a[j]);
    o0[j + 4] = (short)f2bf(b[j]);
    o1[j]     = (short)f2bf(c[j]);
    o1[j + 4] = (short)f2bf(d[j]);
  }
  *(bf16x8*)(xb + i) = o0;
  *(bf16x8*)(xb + i + 8) = o1;
}

// ---------------- w [1024][3072] f32 -> wt [3072][1024] bf16 ----------------
__global__ __launch_bounds__(256) void transpose_w(const float* __restrict__ w,
                                                   unsigned short* __restrict__ wt) {
  __shared__ float tile[32][33];
  const int tx = threadIdx.x & 31, ty = threadIdx.x >> 5;   // 32 x 8
  const int n0 = blockIdx.x * 32, k0 = blockIdx.y * 32;
#pragma unroll
  for (int j = 0; j < 4; j++) {
    int k = ty + j * 8;
    tile[k][tx] = w[(size_t)(k0 + k) * 3072 + n0 + tx];
  }
  __syncthreads();
#pragma unroll
  for (int j = 0; j < 4; j++) {
    int n = ty + j * 8;
    wt[(size_t)(n0 + n) * 1024 + k0 + tx] = f2bf(tile[tx][n]);
  }
}

// ---------------- QKV GEMM: [8192,1024]bf16 x [1024,3072]bf16 -> bf16 qkv ----------------
// BM=BN=128, BK=64, 256 threads (4 waves 2x2, wave tile 64x64), 16x16x32 MFMA.
// LDS linear 16B slots; slot s holds logical (row=s>>3, c=(s&7)^(row&7)):
// global_load_lds dest is linear, source pre-swizzled, reads swizzled (rule 21).
__global__ __launch_bounds__(256) void qkv_gemm(const unsigned short* __restrict__ xb,
                                                const unsigned short* __restrict__ wt,
                                                unsigned short* __restrict__ qkv) {
  __shared__ unsigned short Al[128 * 64];   // 16 KB
  __shared__ unsigned short Bl[128 * 64];   // 16 KB
  const int tid = threadIdx.x;
  const int lane = tid & 63, wid = tid >> 6;
  const int l15 = lane & 15, g = lane >> 4;
  const int m0 = blockIdx.y * 128, n0 = blockIdx.x * 128;
  const int wm = (wid >> 1) * 64, wn = (wid & 1) * 64;

  f32x4 acc[4][4] = {};

  // staging geometry: 1024 slots per matrix, 4 sweeps x 256 threads
  const int srow[4] = { (0 * 256 + tid) >> 3, (1 * 256 + tid) >> 3,
                        (2 * 256 + tid) >> 3, (3 * 256 + tid) >> 3 };
  int scol[4];
#pragma unroll
  for (int sw = 0; sw < 4; sw++) {
    int s = sw * 256 + tid;
    scol[sw] = (s & 7) ^ (srow[sw] & 7);
  }

  for (int k0 = 0; k0 < 1024; k0 += 64) {
    __syncthreads();
#pragma unroll
    for (int sw = 0; sw < 4; sw++) {
      unsigned short* ldsA = &Al[(sw * 256 + wid * 64) * 8];  // wave-uniform base
      unsigned short* ldsB = &Bl[(sw * 256 + wid * 64) * 8];
      gload16(xb + (size_t)(m0 + srow[sw]) * 1024 + k0 + scol[sw] * 8, ldsA);
      gload16(wt + (size_t)(n0 + srow[sw]) * 1024 + k0 + scol[sw] * 8, ldsB);
    }
    __syncthreads();   // compiler drains vmcnt before barrier

#pragma unroll
    for (int ks = 0; ks < 2; ks++) {
      bf16x8 af[4], bfr[4];
#pragma unroll
      for (int mt = 0; mt < 4; mt++) {
        int row = wm + mt * 16 + l15;
        int c = (ks * 4 + g) ^ (row & 7);
        af[mt] = *(const bf16x8*)&Al[(row * 8 + c) * 8];
      }
#pragma unroll
      for (int nt = 0; nt < 4; nt++) {
        int row = wn + nt * 16 + l15;
        int c = (ks * 4 + g) ^ (row & 7);
        bfr[nt] = *(const bf16x8*)&Bl[(row * 8 + c) * 8];
      }
#pragma unroll
      for (int mt = 0; mt < 4; mt++)
#pragma unroll
        for (int nt = 0; nt < 4; nt++)
          acc[mt][nt] = __builtin_amdgcn_mfma_f32_16x16x32_bf16(af[mt], bfr[nt], acc[mt][nt], 0, 0, 0);
    }
  }

  // epilogue: C row=(lane>>4)*4+r, col=lane&15
  const int r0 = g * 4, cc = l15;
#pragma unroll
  for (int mt = 0; mt < 4; mt++)
#pragma unroll
    for (int nt = 0; nt < 4; nt++)
#pragma unroll
      for (int r = 0; r < 4; r++) {
        int m = m0 + wm + mt * 16 + r0 + r;
        int n = n0 + wn + nt * 16 + cc;
        int b = m >> 11, t = m & 2047;
        int which = n >> 10, c = n & 1023;
        int h = c >> 6, d = c & 63;
        qkv[(size_t)which * QKV1 + ((size_t)((b * H_ + h) * T_ + t)) * D_ + d] =
            f2bf(acc[mt][nt][r]);
      }
}

// ---------------- causal flash attention, balanced pairs, fixed-max softmax ----------------
// grid (16, B*H): block xp handles q-tiles {xp, 31-xp} (exactly 33 processings each).
// R1: the two q-tiles of the pair are processed in ONE merged pass per K/V tile so
// the K- and V-fragment ds_read_b128s are issued once and reused (was 2x), and the
// two softmaxes write to separate P buffers so a single lgkmcnt(0) covers both.
// R6: bounds (256,2): VGPR cap ~128 (empirically arg*2 waves/EU budget) ->
// spill-free AND 4 blocks/CU residency.
__global__ __launch_bounds__(256, 2) void attn(const unsigned short* __restrict__ qkv,
                                               float* __restrict__ out) {
  __shared__ unsigned short Kl[64][72];
  __shared__ unsigned short Vl[64][72];         // transposed [d][k], k XOR-swizzled
  __shared__ unsigned short Pl[2][4][16][72];   // per-wave P staging, 2 buffers (b,a)
  const int tid = threadIdx.x, lane = tid & 63, wq = tid >> 6;
  const int l15 = lane & 15, g = lane >> 4;
  const int bh = blockIdx.y;
  const int xp = blockIdx.x;
  const int qta = xp, qtb = 31 - xp;
  const int ntiles = qtb + 1;
  const size_t base = (size_t)bh * (T_ * D_);
  const unsigned short* qp = qkv + base;
  const unsigned short* kp = qkv + (size_t)QKV1 + base;
  const unsigned short* vp = qkv + 2 * (size_t)QKV1 + base;

  bf16x8 qfa[2], qfb[2];
#define LOADQ(QF, Q0)                                                          \
  do {                                                                         \
    int qrow_ = (Q0) + wq * 16 + l15;                                          \
    _Pragma("unroll")                                                          \
    for (int kc = 0; kc < 2; kc++) {                                           \
      bf16x8 v = *(const bf16x8*)(qp + (size_t)qrow_ * 64 + kc * 32 + g * 8);  \
      _Pragma("unroll")                                                        \
      for (int j = 0; j < 8; j++) {                                            \
        unsigned short u = (unsigned short)v[j];                               \
        int e = u & 0x7F80;                                                    \
        u = (e > (3 << 7)) ? (unsigned short)(u - (3 << 7))                    \
                           : (unsigned short)(u & 0x8000);                     \
        v[j] = (short)u;                                                       \
      }                                                                        \
      QF[kc] = v;                                                              \
    }                                                                          \
  } while (0)
  LOADQ(qfa, qta * 64);
  LOADQ(qfb, qtb * 64);

  f32x4 oa[4] = {}, ob[4] = {};
  float rsa[4] = {0.f, 0.f, 0.f, 0.f}, rsb[4] = {0.f, 0.f, 0.f, 0.f};

  bf16x8 kreg0, kreg1, vreg0, vreg1;
  const int krow = tid >> 3, kch = tid & 7;
  const int vpr = tid >> 3, vdch = tid & 7;
#define LOADKV(IT)                                                             \
  do {                                                                         \
    size_t k0_ = (size_t)(IT) * 64;                                            \
    kreg0 = *(const bf16x8*)(kp + (k0_ + krow) * 64 + kch * 8);                \
    kreg1 = *(const bf16x8*)(kp + (k0_ + 32 + krow) * 64 + kch * 8);           \
    vreg0 = *(const bf16x8*)(vp + (k0_ + 2 * vpr) * 64 + vdch * 8);            \
    vreg1 = *(const bf16x8*)(vp + (k0_ + 2 * vpr + 1) * 64 + vdch * 8);        \
  } while (0)

// mask (on diagonal tile), exp, accumulate row-sum, stage P into buffer PBUF
#define SOFTMAX(S, RS, PBUF, Q0, ISDIAG, K0)                                   \
  do {                                                                         \
    if (ISDIAG) {                                                              \
      _Pragma("unroll")                                                        \
      for (int nt = 0; nt < 4; nt++) {                                         \
        int kg_ = (K0) + nt * 16 + l15;                                        \
        _Pragma("unroll")                                                      \
        for (int r = 0; r < 4; r++)                                            \
          if (kg_ > (Q0) + wq * 16 + g * 4 + r) S[nt][r] = -1e30f;             \
      }                                                                        \
    }                                                                          \
    _Pragma("unroll")                                                          \
    for (int nt = 0; nt < 4; nt++)                                             \
      _Pragma("unroll")                                                        \
      for (int r = 0; r < 4; r++) {                                            \
        float p_ = __expf(S[nt][r]);                                           \
        RS[r] += p_;                                                           \
        Pl[PBUF][wq][g * 4 + r][nt * 16 + l15] = f2bf(p_);                     \
      }                                                                        \
  } while (0)

  LOADKV(0);
  for (int it = 0; it < ntiles; ++it) {
    __syncthreads();
    *(bf16x8*)&Kl[krow][kch * 8] = kreg0;
    *(bf16x8*)&Kl[32 + krow][kch * 8] = kreg1;
#pragma unroll
    for (int j = 0; j < 8; j++) {
      int d = vdch * 8 + j;
      unsigned int pk = ((unsigned int)(unsigned short)vreg1[j] << 16) |
                        (unsigned int)(unsigned short)vreg0[j];
      *(unsigned int*)&Vl[d][(2 * vpr) ^ ((d >> 3) << 3)] = pk;
    }
    if (it + 1 < ntiles) LOADKV(it + 1);
    __syncthreads();

    const bool doA = (it <= qta);

    // ---- QK^T for both pair members, sharing the K fragments ----
    f32x4 sb[4], sa[4];
    __builtin_amdgcn_s_setprio(1);
#pragma unroll
    for (int nt = 0; nt < 4; nt++) {
      bf16x8 kf0 = *(const bf16x8*)&Kl[nt * 16 + l15][g * 8];
      bf16x8 kf1 = *(const bf16x8*)&Kl[nt * 16 + l15][32 + g * 8];
      f32x4 t0 = {0.f, 0.f, 0.f, 0.f};
      t0 = __builtin_amdgcn_mfma_f32_16x16x32_bf16(qfb[0], kf0, t0, 0, 0, 0);
      t0 = __builtin_amdgcn_mfma_f32_16x16x32_bf16(qfb[1], kf1, t0, 0, 0, 0);
      sb[nt] = t0;
      if (doA) {
        f32x4 t1 = {0.f, 0.f, 0.f, 0.f};
        t1 = __builtin_amdgcn_mfma_f32_16x16x32_bf16(qfa[0], kf0, t1, 0, 0, 0);
        t1 = __builtin_amdgcn_mfma_f32_16x16x32_bf16(qfa[1], kf1, t1, 0, 0, 0);
        sa[nt] = t1;
      }
    }
    __builtin_amdgcn_s_setprio(0);

    // ---- softmax: b's P-write latency hides under a's VALU work ----
    SOFTMAX(sb, rsb, 0, qtb * 64, it == qtb, it * 64);
    if (doA) SOFTMAX(sa, rsa, 1, qta * 64, it == qta, it * 64);

    asm volatile("s_waitcnt lgkmcnt(0)" ::: "memory");
    bf16x8 pb0 = *(const bf16x8*)&Pl[0][wq][l15][g * 8];
    bf16x8 pb1 = *(const bf16x8*)&Pl[0][wq][l15][32 + g * 8];
    bf16x8 pa0, pa1;
    if (doA) {
      pa0 = *(const bf16x8*)&Pl[1][wq][l15][g * 8];
      pa1 = *(const bf16x8*)&Pl[1][wq][l15][32 + g * 8];
    }

    // ---- PV for both pair members, sharing the V fragments ----
    __builtin_amdgcn_s_setprio(1);
#pragma unroll
    for (int dt = 0; dt < 4; dt++) {
      int d_ = dt * 16 + l15;
      int sw_ = (d_ >> 3) << 3;
      bf16x8 vf0 = *(const bf16x8*)&Vl[d_][(g * 8) ^ sw_];
      bf16x8 vf1 = *(const bf16x8*)&Vl[d_][(32 + g * 8) ^ sw_];
      ob[dt] = __builtin_amdgcn_mfma_f32_16x16x32_bf16(pb0, vf0, ob[dt], 0, 0, 0);
      ob[dt] = __builtin_amdgcn_mfma_f32_16x16x32_bf16(pb1, vf1, ob[dt], 0, 0, 0);
      if (doA) {
        oa[dt] = __builtin_amdgcn_mfma_f32_16x16x32_bf16(pa0, vf0, oa[dt], 0, 0, 0);
        oa[dt] = __builtin_amdgcn_mfma_f32_16x16x32_bf16(pa1, vf1, oa[dt], 0, 0, 0);
      }
    }
    __builtin_amdgcn_s_setprio(0);
  }

  const int b = bh >> 4, h = bh & 15;
#define EPILOG(OACC, RS, Q0)                                                   \
  do {                                                                         \
    _Pragma("unroll")                                                          \
    for (int r = 0; r < 4; r++) {                                              \
      float t_ = RS[r];                                                        \
      t_ += __shfl_xor(t_, 1); t_ += __shfl_xor(t_, 2);                        \
      t_ += __shfl_xor(t_, 4); t_ += __shfl_xor(t_, 8);                        \
      float inv_ = 1.0f / t_;                                                  \
      int qg_ = (Q0) + wq * 16 + g * 4 + r;                                    \
      _Pragma("unroll")                                                        \
      for (int dt = 0; dt < 4; dt++)                                           \
        out[((size_t)(b * T_ + qg_)) * C_ + h * 64 + dt * 16 + l15] =          \
            OACC[dt][r] * inv_;                                                \
    }                                                                          \
  } while (0)
  EPILOG(ob, rsb, qtb * 64);
  EPILOG(oa, rsa, qta * 64);
}

extern "C" void kernel_launch(void* const* d_in, const int* in_sizes, int n_in,
                              void* d_out, int out_size, void* d_ws, size_t ws_size,
                              hipStream_t stream) {
  const float* x = (const float*)d_in[0];
  const float* w = (const float*)d_in[1];
  float* out = (float*)d_out;
  unsigned short* wt  = (unsigned short*)d_ws;            // 3072*1024 bf16 = 6 MB
  unsigned short* qkv = wt + (size_t)3072 * 1024;         // 3 * 8.4M bf16 = 48 MB
  // xb scratch lives in d_out (32 MB f32); attn fully overwrites it afterwards.
  unsigned short* xb  = (unsigned short*)d_out;           // 8192*1024 bf16 = 16 MB

  convert_x  <<<2048, 256, 0, stream>>>(x, xb);
  transpose_w<<<dim3(96, 32), 256, 0, stream>>>(w, wt);
  qkv_gemm   <<<dim3(24, 64), 256, 0, stream>>>(xb, wt, qkv);
  attn       <<<dim3(16, 64), 256, 0, stream>>>(qkv, out);
}